// Round 1
// baseline (609.560 us; speedup 1.0000x reference)
//
#include <hip/hip_runtime.h>
#include <math.h>

// Problem constants (fixed by the reference)
#define BB 256
#define TT 512
#define DD 128
#define HH 128
#define GG 512   // 4*H
#define OO 64

// ---------------------------------------------------------------------------
// Kernel 1: xg[t][g] = dot(x[255,t,:], W_ih[g,:]) + b_ih[g] + b_hh[g]
// Only batch element 255 matters (see launch comment).
// grid = T blocks, block = 512 threads (one per gate)
// ---------------------------------------------------------------------------
__global__ __launch_bounds__(512) void xg_kernel(
    const float* __restrict__ x,
    const float* __restrict__ W_ih,
    const float* __restrict__ b_ih,
    const float* __restrict__ b_hh,
    float* __restrict__ xg)
{
    const int t = blockIdx.x;
    const int g = threadIdx.x;

    __shared__ __align__(16) float xs[DD];
    if (g < DD) xs[g] = x[(255 * TT + t) * DD + g];
    __syncthreads();

    const float4* __restrict__ wrow = (const float4*)(W_ih + g * DD);
    const float4* __restrict__ xv   = (const float4*)xs;

    float a0 = 0.f, a1 = 0.f, a2 = 0.f, a3 = 0.f;
#pragma unroll
    for (int i = 0; i < DD / 4; i += 4) {
        float4 w0 = wrow[i + 0], w1 = wrow[i + 1], w2 = wrow[i + 2], w3 = wrow[i + 3];
        float4 h0 = xv[i + 0],  h1 = xv[i + 1],  h2 = xv[i + 2],  h3 = xv[i + 3];
        a0 += w0.x * h0.x + w0.y * h0.y + w0.z * h0.z + w0.w * h0.w;
        a1 += w1.x * h1.x + w1.y * h1.y + w1.z * h1.z + w1.w * h1.w;
        a2 += w2.x * h2.x + w2.y * h2.y + w2.z * h2.z + w2.w * h2.w;
        a3 += w3.x * h3.x + w3.y * h3.y + w3.z * h3.z + w3.w * h3.w;
    }
    xg[t * GG + g] = (a0 + a1) + (a2 + a3) + b_ih[g] + b_hh[g];
}

// ---------------------------------------------------------------------------
// Kernel 2: sequential LSTM scan for batch 255 only. Single block, 512 thr.
// Thread g owns gate g: W_hh[g,:] lives in 128 VGPRs (32 float4).
// h broadcast via LDS; c persistent in registers of threads 0..127.
// Emits h_t for t in [256,512) to hs (needed by the epilogue MLP).
// ---------------------------------------------------------------------------
__global__ __launch_bounds__(512) void scan_kernel(
    const float* __restrict__ W_hh,
    const float* __restrict__ xg,
    float* __restrict__ hs)
{
    const int g = threadIdx.x;

    __shared__ __align__(16) float h_lds[HH];
    __shared__ __align__(16) float gates[GG];

    // Load this gate's recurrent weight row into registers (one-time, 256 KB total)
    float4 w[32];
    const float4* __restrict__ wrow = (const float4*)(W_hh + g * HH);
#pragma unroll
    for (int i = 0; i < 32; i++) w[i] = wrow[i];

    float c = 0.f;
    if (g < HH) h_lds[g] = 0.f;
    __syncthreads();

    float xg_next = xg[g];  // t = 0 row

    for (int t = 0; t < TT; t++) {
        float acc = xg_next;
        if (t + 1 < TT) xg_next = xg[(t + 1) * GG + g];  // prefetch next row (L2-hot)

        // gate pre-activation: acc += dot(W_hh[g,:], h)
        const float4* __restrict__ hv = (const float4*)h_lds;
        float a0 = 0.f, a1 = 0.f, a2 = 0.f, a3 = 0.f;
#pragma unroll
        for (int i = 0; i < 32; i += 4) {
            float4 h0 = hv[i + 0], h1 = hv[i + 1], h2 = hv[i + 2], h3 = hv[i + 3];
            a0 += w[i + 0].x * h0.x + w[i + 0].y * h0.y + w[i + 0].z * h0.z + w[i + 0].w * h0.w;
            a1 += w[i + 1].x * h1.x + w[i + 1].y * h1.y + w[i + 1].z * h1.z + w[i + 1].w * h1.w;
            a2 += w[i + 2].x * h2.x + w[i + 2].y * h2.y + w[i + 2].z * h2.z + w[i + 2].w * h2.w;
            a3 += w[i + 3].x * h3.x + w[i + 3].y * h3.y + w[i + 3].z * h3.z + w[i + 3].w * h3.w;
        }
        acc += (a0 + a1) + (a2 + a3);

        // activation: gates [2H,3H) are tanh (cell candidate), others sigmoid.
        // g>>7 is wave-uniform (waves 4-5 are the tanh gates) -> no divergence.
        float act;
        if (g >= 2 * HH && g < 3 * HH) {
            act = tanhf(acc);
        } else {
            act = 1.f / (1.f + expf(-acc));
        }
        gates[g] = act;
        __syncthreads();

        if (g < HH) {
            float ig = gates[g];
            float fg = gates[HH + g];
            float gg = gates[2 * HH + g];
            float og = gates[3 * HH + g];
            c = fg * c + ig * gg;
            float h = og * tanhf(c);
            h_lds[g] = h;
            if (t >= 256) hs[(t - 256) * HH + g] = h;
        }
        __syncthreads();
    }
}

// ---------------------------------------------------------------------------
// Kernel 3: out[r, :] = W2 @ (W1 @ hs[r] + b1) + b2   (no activation in ref)
// grid = 256 blocks (one per output row), block = 128 threads
// ---------------------------------------------------------------------------
__global__ __launch_bounds__(128) void mlp_kernel(
    const float* __restrict__ hs,
    const float* __restrict__ W1,
    const float* __restrict__ b1,
    const float* __restrict__ W2,
    const float* __restrict__ b2,
    float* __restrict__ out)
{
    const int r = blockIdx.x;
    const int j = threadIdx.x;

    __shared__ __align__(16) float hsh[HH];
    __shared__ __align__(16) float z[HH];

    hsh[j] = hs[r * HH + j];
    __syncthreads();

    {
        const float4* __restrict__ wrow = (const float4*)(W1 + j * HH);
        const float4* __restrict__ hv   = (const float4*)hsh;
        float acc = b1[j];
#pragma unroll
        for (int i = 0; i < 32; i++) {
            float4 w = wrow[i], h = hv[i];
            acc += w.x * h.x + w.y * h.y + w.z * h.z + w.w * h.w;
        }
        z[j] = acc;
    }
    __syncthreads();

    if (j < OO) {
        const float4* __restrict__ wrow = (const float4*)(W2 + j * HH);
        const float4* __restrict__ zv   = (const float4*)z;
        float acc = b2[j];
#pragma unroll
        for (int i = 0; i < 32; i++) {
            float4 w = wrow[i], zz = zv[i];
            acc += w.x * zz.x + w.y * zz.y + w.z * zz.z + w.w * zz.w;
        }
        out[r * OO + j] = acc;
    }
}

// ---------------------------------------------------------------------------
// Launch. Inputs (setup_inputs order):
//  0: x (B,T,D)  1: W_ih (4H,D)  2: W_hh (4H,H)  3: b_ih (4H)  4: b_hh (4H)
//  5: W1 (H,H)   6: b1 (H)       7: W2 (O,H)     8: b2 (O)
// Output: (B, O) fp32 = 16384 floats.
// Key reduction: y.reshape(T,B,O)[-1] selects b-major flat rows
// (T-1)*B + j  ->  (b=255, t=256+j). Only batch 255's LSTM is needed.
// ---------------------------------------------------------------------------
extern "C" void kernel_launch(void* const* d_in, const int* in_sizes, int n_in,
                              void* d_out, int out_size, void* d_ws, size_t ws_size,
                              hipStream_t stream) {
    const float* x    = (const float*)d_in[0];
    const float* W_ih = (const float*)d_in[1];
    const float* W_hh = (const float*)d_in[2];
    const float* b_ih = (const float*)d_in[3];
    const float* b_hh = (const float*)d_in[4];
    const float* W1   = (const float*)d_in[5];
    const float* b1   = (const float*)d_in[6];
    const float* W2   = (const float*)d_in[7];
    const float* b2   = (const float*)d_in[8];
    float* out = (float*)d_out;

    float* xg = (float*)d_ws;            // T*4H   = 262144 floats (1 MB)
    float* hs = xg + TT * GG;            // 256*H  =  32768 floats (128 KB)

    xg_kernel<<<TT, 512, 0, stream>>>(x, W_ih, b_ih, b_hh, xg);
    scan_kernel<<<1, 512, 0, stream>>>(W_hh, xg, hs);
    mlp_kernel<<<BB, 128, 0, stream>>>(hs, W1, b1, W2, b2, out);
}